// Round 17
// baseline (3933.165 us; speedup 1.0000x reference)
//
#include <hip/hip_runtime.h>
#include <hip/hip_bf16.h>

// GRU autoencoder B=256,T=512,C=64,H=512 — single persistent kernel.
// R17 = R16 geometry + DECENTRALIZED per-chunk dataflow sync:
//   no release barrier, no poller wave. Each wave, per K-chunk, broadcast-polls
//   the producing block's flag (1 line, all lanes same addr) then issues that
//   chunk's 16B h-load — loads overlap later waits; one vmcnt(0) before MFMA.
//   Write-after-read guard is transitive: kh0 waves wait blocks 0..7(0..6 enc),
//   kh1 wait 8..15(7..15 enc); consol barrier joins all 4 waves => all 16
//   producer flags >= step observed before streamer overwrites read buffer.
// 16 groups x 16 rows; 16 blocks/group (grid=256); block=16 rows x 128 cols;
// waves = (kh K-half) x (ch col-half); 36-frag weights/wave.
// h exchange: 16B sc0 sc1 (R13-proven). Flags agent-scope, own 128B lines.

#define B_ 256
#define T_ 512
#define C_ 64
#define H_ 512
#define TC_ 32768   // T_*C_
#define BH_ 131072  // B_*H_

typedef __attribute__((ext_vector_type(8))) short s16x8;
typedef __attribute__((ext_vector_type(4))) float f32x4;
typedef __attribute__((ext_vector_type(4))) unsigned int u32x4;

__device__ __forceinline__ unsigned short f2b(float f) {
    unsigned int u = __float_as_uint(f);
    unsigned int r = (u + 0x7FFFu + ((u >> 16) & 1u)) >> 16;
    return (unsigned short)r;
}
__device__ __forceinline__ float sigm(float v) {
    return __builtin_amdgcn_rcpf(1.f + __expf(-v));
}
__device__ __forceinline__ float ftanh(float v) {
    float a = fabsf(v);
    float e = __expf(-2.f * a);
    float t = (1.f - e) * __builtin_amdgcn_rcpf(1.f + e);
    return copysignf(t, v);
}
// 16B LLC-coherent load/store (R13-proven). Caller must emit
// s_waitcnt vmcnt(0) + sched_barrier(0) before consuming loads (rule #18).
__device__ __forceinline__ s16x8 ldh16a(const unsigned short* p) {
    u32x4 r;
    asm volatile("global_load_dwordx4 %0, %1, off sc0 sc1" : "=v"(r) : "v"(p));
    return __builtin_bit_cast(s16x8, r);
}
__device__ __forceinline__ void sth16a(unsigned short* p, u32x4 v) {
    asm volatile("global_store_dwordx4 %0, %1, off sc0 sc1" :: "v"(p), "v"(v) : "memory");
}

// ---------------- weight prep kernels (validated R1..R16) ----------------

__global__ __launch_bounds__(256) void prep_enc_k(
    const float* __restrict__ Wih, const float* __restrict__ Whh,
    const float* __restrict__ bih, const float* __restrict__ bhh,
    unsigned short* __restrict__ W, float* __restrict__ bias)
{
    int idx = blockIdx.x * 256 + threadIdx.x;
    if (idx >= 2048 * 576) return;
    int n = idx / 576, k = idx % 576;
    int part = (n >> 4) & 3, jc = n & 15, j16 = n >> 6;
    int j = j16 * 16 + jc;
    float v;
    if (part == 0)      v = (k < 64) ? Wih[j * 64 + k]          : Whh[(size_t)j * 512 + (k - 64)];
    else if (part == 1) v = (k < 64) ? Wih[(512 + j) * 64 + k]  : Whh[(size_t)(512 + j) * 512 + (k - 64)];
    else if (part == 2) v = (k < 64) ? Wih[(1024 + j) * 64 + k] : 0.f;
    else                v = (k < 64) ? 0.f                       : Whh[(size_t)(1024 + j) * 512 + (k - 64)];
    W[(size_t)n * 576 + k] = f2b(v);
    if (k == 0) {
        float b;
        if (part == 0)      b = bih[j] + bhh[j];
        else if (part == 1) b = bih[512 + j] + bhh[512 + j];
        else if (part == 2) b = bih[1024 + j];
        else                b = bhh[1024 + j];
        bias[n] = b;
    }
}

__global__ __launch_bounds__(256) void prep_dec_k(
    const float* __restrict__ Wih, const float* __restrict__ Whh,
    const float* __restrict__ Wout,
    unsigned short* __restrict__ W1, unsigned short* __restrict__ W0)
{
    int n = blockIdx.x;
    __shared__ float wrow[64];
    bool isout = (n >= 2048);
    int part = 0, j = 0, n3 = 0;
    if (!isout) {
        part = (n >> 4) & 3;
        int jc = n & 15, j16 = n >> 6;
        j = j16 * 16 + jc;
        n3 = (part == 0) ? j : (part == 1) ? (512 + j) : (1024 + j);
    }
    if (threadIdx.x < 64 && !isout && part != 3)
        wrow[threadIdx.x] = Wih[n3 * 64 + threadIdx.x];
    __syncthreads();
    for (int kk = 0; kk < 2; ++kk) {
        int k = kk * 256 + threadIdx.x;
        float v1, v0;
        if (isout) {
            v1 = v0 = Wout[(size_t)(n - 2048) * 512 + k];
        } else if (part == 3) {
            v1 = v0 = Whh[(size_t)(1024 + j) * 512 + k];
        } else {
            float af = 0.f;
            #pragma unroll
            for (int c = 0; c < 64; ++c) af += wrow[c] * Wout[(size_t)c * 512 + k];
            if (part == 2) { v1 = af; v0 = 0.f; }
            else { float wh = Whh[(size_t)n3 * 512 + k]; v1 = af + wh; v0 = wh; }
        }
        W1[(size_t)n * 512 + k] = f2b(v1);
        W0[(size_t)n * 512 + k] = f2b(v0);
    }
}

__global__ __launch_bounds__(256) void prep_dec_bias_k(
    const float* __restrict__ Wih, const float* __restrict__ bih,
    const float* __restrict__ bhh, const float* __restrict__ bout,
    float* __restrict__ b1, float* __restrict__ b0)
{
    int n = blockIdx.x * 256 + threadIdx.x;
    if (n >= 2112) return;
    if (n >= 2048) { b1[n] = bout[n - 2048]; b0[n] = bout[n - 2048]; return; }
    int part = (n >> 4) & 3, jc = n & 15, j16 = n >> 6;
    int j = j16 * 16 + jc;
    float v1, v0;
    if (part == 3) { v1 = v0 = bhh[1024 + j]; }
    else {
        int n3 = (part == 0) ? j : (part == 1) ? (512 + j) : (1024 + j);
        float wib = 0.f;
        #pragma unroll
        for (int c = 0; c < 64; ++c) wib += Wih[n3 * 64 + c] * bout[c];
        if (part == 2) { v1 = bih[1024 + j] + wib; v0 = bih[1024 + j]; }
        else { float base = bih[n3] + bhh[n3]; v1 = base + wib; v0 = base; }
    }
    b1[n] = v1; b0[n] = v0;
}

// ---------------- persistent recurrence kernel ----------------

// Broadcast poll one flag line (all lanes same address -> 1 transaction/iter).
__device__ __forceinline__ void wait_flag1(const unsigned int* fp, unsigned int tgt) {
    while (__hip_atomic_load(fp, __ATOMIC_RELAXED, __HIP_MEMORY_SCOPE_AGENT) < tgt) {}
    asm volatile("" ::: "memory");
    __builtin_amdgcn_sched_barrier(0);
}
// Lane-parallel wait on the group's 16 flags (tail use only).
template<bool SLEEP>
__device__ __forceinline__ void wait_flags16(const unsigned int* fl, int lane, unsigned int tgt) {
    const unsigned int* fp = fl + (lane & 15) * 32;
    while (true) {
        unsigned int fv = __hip_atomic_load(fp, __ATOMIC_RELAXED, __HIP_MEMORY_SCOPE_AGENT);
        if (__all(fv >= tgt)) break;
        if (SLEEP) __builtin_amdgcn_s_sleep(1);
    }
    asm volatile("" ::: "memory");
    __builtin_amdgcn_sched_barrier(0);
}

// One step of one wave: 16 rows x 64 gate cols, half K. NK=18 enc, 16 dec.
// Per-chunk: poll producer flag -> issue 16B h-load -> next (loads overlap).
template<int NK, bool PRED>
__device__ __forceinline__ void do_step(
    const unsigned short* __restrict__ hin, unsigned short* __restrict__ hout,
    const s16x8 (&bfr)[36], const s16x8 (&pfr)[8], const float4 (&xf)[2][2],
    const float* bR, float bp, float (&h32)[4],
    float* __restrict__ out, int tout,
    const unsigned int* __restrict__ fl, unsigned int* __restrict__ flagp, int step,
    int r0, int j, int kh, int ch, int lane, bool duty,
    float (*Ored)[64][20], unsigned short (*Hst)[32])
{
    constexpr int HK = NK / 2;
    const int jc = lane & 15, kq = lane >> 4;
    const int ks0 = kh * HK;
    const unsigned short* hrow = hin + (size_t)(r0 + jc) * H_;

    s16x8 af[HK];
    if (NK == 18 && kh == 0) {
        #pragma unroll
        for (int i2 = 0; i2 < 2; ++i2) {
            s16x8 v;
            v[0] = (short)f2b(xf[i2][0].x); v[1] = (short)f2b(xf[i2][0].y);
            v[2] = (short)f2b(xf[i2][0].z); v[3] = (short)f2b(xf[i2][0].w);
            v[4] = (short)f2b(xf[i2][1].x); v[5] = (short)f2b(xf[i2][1].y);
            v[6] = (short)f2b(xf[i2][1].z); v[7] = (short)f2b(xf[i2][1].w);
            af[i2] = v;
        }
    }
    // per-chunk: wait producing block's flag (broadcast), then ISSUE the load
    #pragma unroll
    for (int i = 0; i < HK; ++i) {
        const int gks = ks0 + i;
        const bool isx = (NK == 18) && (gks < 2);
        if (!isx) {
            const int hb = (NK == 18) ? (gks - 2) : gks;   // producer block
            if (step > 0) wait_flag1(fl + hb * 32, (unsigned int)step);
            af[i] = ldh16a(hrow + hb * 32 + kq * 8);
        }
    }
    // rule #18: asm loads are not compiler-tracked — wait + fence before MFMA
    asm volatile("s_waitcnt vmcnt(0)" ::: "memory");
    __builtin_amdgcn_sched_barrier(0);

    f32x4 acc[4] = {{0,0,0,0},{0,0,0,0},{0,0,0,0},{0,0,0,0}};
    f32x4 pacc = {0,0,0,0};
    const bool pduty = PRED && duty && (ch == 0);
    #pragma unroll
    for (int i = 0; i < HK; ++i) {
        #pragma unroll
        for (int q = 0; q < 4; ++q)
            acc[q] = __builtin_amdgcn_mfma_f32_16x16x32_bf16(af[i], bfr[i * 4 + q], acc[q], 0, 0, 0);
        if (pduty)
            pacc = __builtin_amdgcn_mfma_f32_16x16x32_bf16(af[i], pfr[i], pacc, 0, 0, 0);
    }

    if (kh == 1) {
        #pragma unroll
        for (int q = 0; q < 4; ++q) *(f32x4*)&Ored[ch][lane][q * 4] = acc[q];
        if (pduty) *(f32x4*)&Ored[0][lane][16] = pacc;
    }
    asm volatile("s_waitcnt lgkmcnt(0)" ::: "memory");
    __builtin_amdgcn_s_barrier();   // mid-step: K-half partials in LDS
    __builtin_amdgcn_sched_barrier(0);

    if (kh == 0) {
        #pragma unroll
        for (int q = 0; q < 4; ++q) {
            f32x4 o = *(const f32x4*)&Ored[ch][lane][q * 4];
            acc[q] = acc[q] + o;
        }
        if (pduty) {
            f32x4 o = *(const f32x4*)&Ored[0][lane][16];
            pacc = pacc + o;
        }
        float hn[4];
        #pragma unroll
        for (int r = 0; r < 4; ++r) {
            float gr = acc[0][r] + bR[0];
            float gz = acc[1][r] + bR[1];
            float gi = acc[2][r] + bR[2];
            float gh = acc[3][r] + bR[3];
            float rg = sigm(gr), zg = sigm(gz);
            float ng = ftanh(gi + rg * gh);
            hn[r] = (1.f - zg) * ng + zg * h32[r];
            h32[r] = hn[r];
        }
        #pragma unroll
        for (int r = 0; r < 4; ++r) Hst[kq * 4 + r][ch * 16 + jc] = f2b(hn[r]);
    }
    // consolidation barrier: all 4 waves done -> (a) Hst complete for streamer,
    // (b) TRANSITIVE write-guard: every wave observed its half's producer flags
    // >= step, union = all 16 -> safe to overwrite the read buffer of step-1.
    asm volatile("s_waitcnt lgkmcnt(0)" ::: "memory");
    __builtin_amdgcn_s_barrier();
    __builtin_amdgcn_sched_barrier(0);

    if (kh == 0 && ch == 0) {
        // streamer: 16 rows x 64B (one 16B transaction per lane), one drain,
        // ONE flag on this block's own 128B line
        const int row = lane >> 2, quarter = lane & 3;
        u32x4 hv = *(const u32x4*)&Hst[row][quarter * 8];
        sth16a(hout + (size_t)(r0 + row) * H_ + j * 32 + quarter * 8, hv);
        asm volatile("s_waitcnt vmcnt(0)" ::: "memory");   // h at coherence point
        if (lane == 0)
            __hip_atomic_store(flagp, (unsigned int)(step + 1),
                               __ATOMIC_RELAXED, __HIP_MEMORY_SCOPE_AGENT);
        // out stores off the recurrence critical path
        if (PRED && duty) {
            #pragma unroll
            for (int r = 0; r < 4; ++r)
                out[(size_t)(r0 + kq * 4 + r) * TC_ + (size_t)tout * C_ + j * 16 + jc] = pacc[r] + bp;
        }
    }
}

__global__ __launch_bounds__(256, 1) void gru_persist(
    const unsigned short* __restrict__ WencT,
    const unsigned short* __restrict__ WdecT,
    const unsigned short* __restrict__ Wdec0T,
    const float* __restrict__ benc, const float* __restrict__ bdec, const float* __restrict__ bdec0,
    const float* __restrict__ x,
    unsigned short* __restrict__ h16,
    float* __restrict__ out,
    unsigned int* __restrict__ flags)
{
    __shared__ __align__(16) float Ored[2][64][20];
    __shared__ __align__(16) unsigned short Hst[16][32];

    const int bid = blockIdx.x;
    const int g = bid & 15, j = bid >> 4;   // group, block-in-group
    const int tid = threadIdx.x;
    const int c = tid >> 6, lane = tid & 63;
    const int kh = c & 1, ch = c >> 1;
    const int jc = lane & 15, kq = lane >> 4;
    const int r0 = g * 16;
    const bool duty = (j < 4);
    unsigned int* fl = flags + g * 16 * 32;   // 16 flags x 32-dword stride
    unsigned int* flagp = fl + j * 32;        // this block's own 128B line
    const int n0 = j * 128 + ch * 64;         // this wave's 64 gate cols

    float be[4], bd[4], bd0[4];
    #pragma unroll
    for (int q = 0; q < 4; ++q) {
        be[q]  = benc[n0 + q * 16 + jc];
        bd[q]  = bdec[n0 + q * 16 + jc];
        bd0[q] = bdec0[n0 + q * 16 + jc];
    }
    const float bp = duty ? bdec[2048 + j * 16 + jc] : 0.f;

    // half-K encoder weights in registers (36 frags, proven footprint)
    s16x8 bfr[36];
    #pragma unroll
    for (int i = 0; i < 9; ++i) {
        const int gks = kh * 9 + i;
        #pragma unroll
        for (int q = 0; q < 4; ++q)
            bfr[i * 4 + q] = *(const s16x8*)(WencT + (size_t)(n0 + q * 16 + jc) * 576 + gks * 32 + kq * 8);
    }
    s16x8 pfr[8];
    #pragma unroll
    for (int i = 0; i < 8; ++i) pfr[i] = s16x8{0,0,0,0,0,0,0,0};

    float h32[4] = {0.f, 0.f, 0.f, 0.f};
    int parity = 0;
    float4 xf[2][2];

    for (int step = 0; step < 1024; ++step) {
        const bool enc = step < 512;
        // early x issue (kh0 waves; in flight during chunk-flag waits)
        if (enc && kh == 0) {
            const float* xp = x + (size_t)(r0 + jc) * TC_ + (size_t)step * C_ + kq * 8;
            #pragma unroll
            for (int i2 = 0; i2 < 2; ++i2) {
                xf[i2][0] = *(const float4*)(xp + i2 * 32);
                xf[i2][1] = *(const float4*)(xp + i2 * 32 + 4);
            }
        }
        // phase-change weight reloads (one-time; overlap the waits)
        if (step == 512) {
            #pragma unroll
            for (int i = 0; i < 8; ++i) {
                const int gks = kh * 8 + i;
                #pragma unroll
                for (int q = 0; q < 4; ++q)
                    bfr[i * 4 + q] = *(const s16x8*)(Wdec0T + (size_t)(n0 + q * 16 + jc) * 512 + gks * 32 + kq * 8);
                if (duty && ch == 0)
                    pfr[i] = *(const s16x8*)(WdecT + (size_t)(2048 + j * 16 + jc) * 512 + gks * 32 + kq * 8);
            }
        } else if (step == 513) {
            #pragma unroll
            for (int i = 0; i < 8; ++i) {
                const int gks = kh * 8 + i;
                #pragma unroll
                for (int q = 0; q < 4; ++q)
                    bfr[i * 4 + q] = *(const s16x8*)(WdecT + (size_t)(n0 + q * 16 + jc) * 512 + gks * 32 + kq * 8);
            }
        }
        // NO release barrier: per-chunk dataflow waits inside do_step.

        const unsigned short* hin = h16 + (size_t)parity * BH_;
        unsigned short* hout = h16 + (size_t)(parity ^ 1) * BH_;

        if (enc)
            do_step<18, false>(hin, hout, bfr, pfr, xf, be,  bp, h32, out, 0,
                               fl, flagp, step, r0, j, kh, ch, lane, duty, Ored, Hst);
        else if (step == 512)
            do_step<16, false>(hin, hout, bfr, pfr, xf, bd0, bp, h32, out, 0,
                               fl, flagp, step, r0, j, kh, ch, lane, duty, Ored, Hst);
        else
            do_step<16, true >(hin, hout, bfr, pfr, xf, bd,  bp, h32, out, step - 513,
                               fl, flagp, step, r0, j, kh, ch, lane, duty, Ored, Hst);

        parity ^= 1;
    }

    // final pred_{511} from h after last step (duty blocks only)
    if (duty) {
        wait_flags16<true>(fl, lane, 1024u);
        const unsigned short* hin = h16 + (size_t)parity * BH_;
        const unsigned short* hrow = hin + (size_t)(r0 + jc) * H_;
        f32x4 pacc = {0, 0, 0, 0};
        if (ch == 0) {
            s16x8 hf[8];
            #pragma unroll
            for (int i = 0; i < 8; ++i) {
                const int gks = kh * 8 + i;
                hf[i] = ldh16a(hrow + gks * 32 + kq * 8);
            }
            asm volatile("s_waitcnt vmcnt(0)" ::: "memory");
            __builtin_amdgcn_sched_barrier(0);
            #pragma unroll
            for (int i = 0; i < 8; ++i)
                pacc = __builtin_amdgcn_mfma_f32_16x16x32_bf16(hf[i], pfr[i], pacc, 0, 0, 0);
            if (kh == 1) *(f32x4*)&Ored[0][lane][16] = pacc;
        }
        asm volatile("s_waitcnt lgkmcnt(0)" ::: "memory");
        __builtin_amdgcn_s_barrier();
        __builtin_amdgcn_sched_barrier(0);
        if (kh == 0 && ch == 0) {
            f32x4 o = *(const f32x4*)&Ored[0][lane][16];
            pacc = pacc + o;
            #pragma unroll
            for (int r = 0; r < 4; ++r)
                out[(size_t)(r0 + kq * 4 + r) * TC_ + (size_t)511 * C_ + j * 16 + jc] = pacc[r] + bp;
        }
    }
}

// ---------------- host launcher ----------------

extern "C" void kernel_launch(void* const* d_in, const int* in_sizes, int n_in,
                              void* d_out, int out_size, void* d_ws, size_t ws_size,
                              hipStream_t stream) {
    const float* x    = (const float*)d_in[0];
    const float* eWih = (const float*)d_in[1];
    const float* eWhh = (const float*)d_in[2];
    const float* ebih = (const float*)d_in[3];
    const float* ebhh = (const float*)d_in[4];
    const float* dWih = (const float*)d_in[5];
    const float* dWhh = (const float*)d_in[6];
    const float* dbih = (const float*)d_in[7];
    const float* dbhh = (const float*)d_in[8];
    const float* Wout = (const float*)d_in[9];
    const float* bout = (const float*)d_in[10];

    size_t off = 0;
    auto carve = [&](size_t bytes) -> void* {
        off = (off + 255) & ~(size_t)255;
        void* p = (char*)d_ws + off;
        off += bytes;
        return p;
    };
    unsigned short* WencT  = (unsigned short*)carve((size_t)2048 * 576 * 2);
    unsigned short* WdecT  = (unsigned short*)carve((size_t)2112 * 512 * 2);
    unsigned short* Wdec0T = (unsigned short*)carve((size_t)2112 * 512 * 2);
    float* benc  = (float*)carve(2048 * 4);
    float* bdec  = (float*)carve(2112 * 4);
    float* bdec0 = (float*)carve(2112 * 4);
    unsigned short* h16 = (unsigned short*)carve((size_t)2 * BH_ * 2);
    unsigned int* flags = (unsigned int*)carve(16 * 16 * 32 * 4);  // 1 flag/block, own 128B line

    hipMemsetAsync(h16, 0, (size_t)2 * BH_ * 2, stream);
    hipMemsetAsync(flags, 0, 16 * 16 * 32 * 4, stream);

    prep_enc_k<<<(2048 * 576 + 255) / 256, 256, 0, stream>>>(eWih, eWhh, ebih, ebhh, WencT, benc);
    prep_dec_k<<<2112, 256, 0, stream>>>(dWih, dWhh, Wout, WdecT, Wdec0T);
    prep_dec_bias_k<<<9, 256, 0, stream>>>(dWih, dbih, dbhh, bout, bdec, bdec0);

    gru_persist<<<256, 256, 0, stream>>>(WencT, WdecT, Wdec0T, benc, bdec, bdec0,
                                         x, h16, (float*)d_out, flags);
}

// Round 18
// 3199.732 us; speedup vs baseline: 1.2292x; 1.2292x over previous
//
#include <hip/hip_runtime.h>
#include <hip/hip_bf16.h>

// GRU autoencoder B=256,T=512,C=64,H=512 — single persistent kernel.
// R18 = R16 + overlapped detection (relay): wave c1 (kh1,ch0), idle after the
// mid-step barrier, polls the group's 16 flags for step+1 DURING the producer
// tail and publishes via LDS word `rel`. Consolidation + release s_barriers
// replaced by LDS spins (hd1: kh0ch1 -> streamer; rel: c1 -> all).
// Only the mid-step s_barrier remains. Dependency chain is strictly monotone
// (rel(s+1) <- flags(s+1) <- streamers(s) <- cell(s) <- midbar(s) <- rel(s)).
// Geometry/exchange identical to R16: 16 groups x 16 rows, 16 blocks/group,
// block=16 rows x 128 gate cols, waves=(kh)x(ch), 36-frag weights/wave,
// 16B sc0 sc1 h exchange, agent flags on own 128B lines.

#define B_ 256
#define T_ 512
#define C_ 64
#define H_ 512
#define TC_ 32768   // T_*C_
#define BH_ 131072  // B_*H_

typedef __attribute__((ext_vector_type(8))) short s16x8;
typedef __attribute__((ext_vector_type(4))) float f32x4;
typedef __attribute__((ext_vector_type(4))) unsigned int u32x4;

__device__ __forceinline__ unsigned short f2b(float f) {
    unsigned int u = __float_as_uint(f);
    unsigned int r = (u + 0x7FFFu + ((u >> 16) & 1u)) >> 16;
    return (unsigned short)r;
}
__device__ __forceinline__ float sigm(float v) {
    return __builtin_amdgcn_rcpf(1.f + __expf(-v));
}
__device__ __forceinline__ float ftanh(float v) {
    float a = fabsf(v);
    float e = __expf(-2.f * a);
    float t = (1.f - e) * __builtin_amdgcn_rcpf(1.f + e);
    return copysignf(t, v);
}
// 16B LLC-coherent load/store (R13-proven). Caller must emit
// s_waitcnt vmcnt(0) + sched_barrier(0) before consuming loads (rule #18).
__device__ __forceinline__ s16x8 ldh16a(const unsigned short* p) {
    u32x4 r;
    asm volatile("global_load_dwordx4 %0, %1, off sc0 sc1" : "=v"(r) : "v"(p));
    return __builtin_bit_cast(s16x8, r);
}
__device__ __forceinline__ void sth16a(unsigned short* p, u32x4 v) {
    asm volatile("global_store_dwordx4 %0, %1, off sc0 sc1" :: "v"(p), "v"(v) : "memory");
}
// LDS spin helpers (workgroup scope; broadcast reads, ~cheap)
__device__ __forceinline__ void lds_signal(unsigned int* p, unsigned int v) {
    __hip_atomic_store(p, v, __ATOMIC_RELAXED, __HIP_MEMORY_SCOPE_WORKGROUP);
}
__device__ __forceinline__ void lds_wait(const unsigned int* p, unsigned int tgt) {
    while (__hip_atomic_load(p, __ATOMIC_RELAXED, __HIP_MEMORY_SCOPE_WORKGROUP) < tgt) {}
    asm volatile("" ::: "memory");
    __builtin_amdgcn_sched_barrier(0);
}

// ---------------- weight prep kernels (validated R1..R16) ----------------

__global__ __launch_bounds__(256) void prep_enc_k(
    const float* __restrict__ Wih, const float* __restrict__ Whh,
    const float* __restrict__ bih, const float* __restrict__ bhh,
    unsigned short* __restrict__ W, float* __restrict__ bias)
{
    int idx = blockIdx.x * 256 + threadIdx.x;
    if (idx >= 2048 * 576) return;
    int n = idx / 576, k = idx % 576;
    int part = (n >> 4) & 3, jc = n & 15, j16 = n >> 6;
    int j = j16 * 16 + jc;
    float v;
    if (part == 0)      v = (k < 64) ? Wih[j * 64 + k]          : Whh[(size_t)j * 512 + (k - 64)];
    else if (part == 1) v = (k < 64) ? Wih[(512 + j) * 64 + k]  : Whh[(size_t)(512 + j) * 512 + (k - 64)];
    else if (part == 2) v = (k < 64) ? Wih[(1024 + j) * 64 + k] : 0.f;
    else                v = (k < 64) ? 0.f                       : Whh[(size_t)(1024 + j) * 512 + (k - 64)];
    W[(size_t)n * 576 + k] = f2b(v);
    if (k == 0) {
        float b;
        if (part == 0)      b = bih[j] + bhh[j];
        else if (part == 1) b = bih[512 + j] + bhh[512 + j];
        else if (part == 2) b = bih[1024 + j];
        else                b = bhh[1024 + j];
        bias[n] = b;
    }
}

__global__ __launch_bounds__(256) void prep_dec_k(
    const float* __restrict__ Wih, const float* __restrict__ Whh,
    const float* __restrict__ Wout,
    unsigned short* __restrict__ W1, unsigned short* __restrict__ W0)
{
    int n = blockIdx.x;
    __shared__ float wrow[64];
    bool isout = (n >= 2048);
    int part = 0, j = 0, n3 = 0;
    if (!isout) {
        part = (n >> 4) & 3;
        int jc = n & 15, j16 = n >> 6;
        j = j16 * 16 + jc;
        n3 = (part == 0) ? j : (part == 1) ? (512 + j) : (1024 + j);
    }
    if (threadIdx.x < 64 && !isout && part != 3)
        wrow[threadIdx.x] = Wih[n3 * 64 + threadIdx.x];
    __syncthreads();
    for (int kk = 0; kk < 2; ++kk) {
        int k = kk * 256 + threadIdx.x;
        float v1, v0;
        if (isout) {
            v1 = v0 = Wout[(size_t)(n - 2048) * 512 + k];
        } else if (part == 3) {
            v1 = v0 = Whh[(size_t)(1024 + j) * 512 + k];
        } else {
            float af = 0.f;
            #pragma unroll
            for (int c = 0; c < 64; ++c) af += wrow[c] * Wout[(size_t)c * 512 + k];
            if (part == 2) { v1 = af; v0 = 0.f; }
            else { float wh = Whh[(size_t)n3 * 512 + k]; v1 = af + wh; v0 = wh; }
        }
        W1[(size_t)n * 512 + k] = f2b(v1);
        W0[(size_t)n * 512 + k] = f2b(v0);
    }
}

__global__ __launch_bounds__(256) void prep_dec_bias_k(
    const float* __restrict__ Wih, const float* __restrict__ bih,
    const float* __restrict__ bhh, const float* __restrict__ bout,
    float* __restrict__ b1, float* __restrict__ b0)
{
    int n = blockIdx.x * 256 + threadIdx.x;
    if (n >= 2112) return;
    if (n >= 2048) { b1[n] = bout[n - 2048]; b0[n] = bout[n - 2048]; return; }
    int part = (n >> 4) & 3, jc = n & 15, j16 = n >> 6;
    int j = j16 * 16 + jc;
    float v1, v0;
    if (part == 3) { v1 = v0 = bhh[1024 + j]; }
    else {
        int n3 = (part == 0) ? j : (part == 1) ? (512 + j) : (1024 + j);
        float wib = 0.f;
        #pragma unroll
        for (int c = 0; c < 64; ++c) wib += Wih[n3 * 64 + c] * bout[c];
        if (part == 2) { v1 = bih[1024 + j] + wib; v0 = bih[1024 + j]; }
        else { float base = bih[n3] + bhh[n3]; v1 = base + wib; v0 = base; }
    }
    b1[n] = v1; b0[n] = v0;
}

// ---------------- persistent recurrence kernel ----------------

// Lane-parallel wait on the group's 16 flags (R16-proven shape).
template<bool SLEEP>
__device__ __forceinline__ void wait_flags16(const unsigned int* fl, int lane, unsigned int tgt) {
    const unsigned int* fp = fl + (lane & 15) * 32;
    while (true) {
        unsigned int fv = __hip_atomic_load(fp, __ATOMIC_RELAXED, __HIP_MEMORY_SCOPE_AGENT);
        if (__all(fv >= tgt)) break;
        if (SLEEP) __builtin_amdgcn_s_sleep(1);
    }
    asm volatile("" ::: "memory");
    __builtin_amdgcn_sched_barrier(0);
}

// One step of one wave: 16 rows x 64 gate cols, half K. NK=18 enc, 16 dec.
template<int NK, bool PRED>
__device__ __forceinline__ void do_step(
    const unsigned short* __restrict__ hin, unsigned short* __restrict__ hout,
    const s16x8 (&bfr)[36], const s16x8 (&pfr)[8], const float4 (&xf)[2][2],
    const float* bR, float bp, float (&h32)[4],
    float* __restrict__ out, int tout,
    const unsigned int* __restrict__ fl, unsigned int* __restrict__ flagp, int step,
    int r0, int j, int kh, int ch, int lane, bool duty,
    float (*Ored)[64][20], unsigned short (*Hst)[32],
    unsigned int* rel, unsigned int* hd1)
{
    constexpr int HK = NK / 2;
    const int jc = lane & 15, kq = lane >> 4;
    const int ks0 = kh * HK;
    const unsigned short* hrow = hin + (size_t)(r0 + jc) * H_;

    s16x8 af[HK];
    if (NK == 18 && kh == 0) {
        #pragma unroll
        for (int i2 = 0; i2 < 2; ++i2) {
            s16x8 v;
            v[0] = (short)f2b(xf[i2][0].x); v[1] = (short)f2b(xf[i2][0].y);
            v[2] = (short)f2b(xf[i2][0].z); v[3] = (short)f2b(xf[i2][0].w);
            v[4] = (short)f2b(xf[i2][1].x); v[5] = (short)f2b(xf[i2][1].y);
            v[6] = (short)f2b(xf[i2][1].z); v[7] = (short)f2b(xf[i2][1].w);
            af[i2] = v;
        }
    }
    #pragma unroll
    for (int i = 0; i < HK; ++i) {
        const int gks = ks0 + i;
        const bool isx = (NK == 18) && (gks < 2);
        if (!isx) {
            const int hk = ((NK == 18) ? (gks - 2) : gks) * 32 + kq * 8;
            af[i] = ldh16a(hrow + hk);
        }
    }
    // rule #18: asm loads are not compiler-tracked — wait + fence before MFMA
    asm volatile("s_waitcnt vmcnt(0)" ::: "memory");
    __builtin_amdgcn_sched_barrier(0);

    f32x4 acc[4] = {{0,0,0,0},{0,0,0,0},{0,0,0,0},{0,0,0,0}};
    f32x4 pacc = {0,0,0,0};
    const bool pduty = PRED && duty && (ch == 0);
    #pragma unroll
    for (int i = 0; i < HK; ++i) {
        #pragma unroll
        for (int q = 0; q < 4; ++q)
            acc[q] = __builtin_amdgcn_mfma_f32_16x16x32_bf16(af[i], bfr[i * 4 + q], acc[q], 0, 0, 0);
        if (pduty)
            pacc = __builtin_amdgcn_mfma_f32_16x16x32_bf16(af[i], pfr[i], pacc, 0, 0, 0);
    }

    if (kh == 1) {
        #pragma unroll
        for (int q = 0; q < 4; ++q) *(f32x4*)&Ored[ch][lane][q * 4] = acc[q];
        if (pduty) *(f32x4*)&Ored[0][lane][16] = pacc;
    }
    asm volatile("s_waitcnt lgkmcnt(0)" ::: "memory");
    __builtin_amdgcn_s_barrier();   // mid-step: K-half partials in LDS (ONLY barrier)
    __builtin_amdgcn_sched_barrier(0);

    if (kh == 0) {
        #pragma unroll
        for (int q = 0; q < 4; ++q) {
            f32x4 o = *(const f32x4*)&Ored[ch][lane][q * 4];
            acc[q] = acc[q] + o;
        }
        if (pduty) {
            f32x4 o = *(const f32x4*)&Ored[0][lane][16];
            pacc = pacc + o;
        }
        float hn[4];
        #pragma unroll
        for (int r = 0; r < 4; ++r) {
            float gr = acc[0][r] + bR[0];
            float gz = acc[1][r] + bR[1];
            float gi = acc[2][r] + bR[2];
            float gh = acc[3][r] + bR[3];
            float rg = sigm(gr), zg = sigm(gz);
            float ng = ftanh(gi + rg * gh);
            hn[r] = (1.f - zg) * ng + zg * h32[r];
            h32[r] = hn[r];
        }
        #pragma unroll
        for (int r = 0; r < 4; ++r) Hst[kq * 4 + r][ch * 16 + jc] = f2b(hn[r]);
        asm volatile("s_waitcnt lgkmcnt(0)" ::: "memory");   // Hst visible in LDS
        __builtin_amdgcn_sched_barrier(0);
        if (ch == 1) {
            if (lane == 0) lds_signal(hd1, (unsigned int)(step + 1));
        } else {
            // streamer (kh0ch0): wait partner half, stream 1KB, drain, flag
            lds_wait(hd1, (unsigned int)(step + 1));
            const int row = lane >> 2, quarter = lane & 3;
            u32x4 hv = *(const u32x4*)&Hst[row][quarter * 8];
            sth16a(hout + (size_t)(r0 + row) * H_ + j * 32 + quarter * 8, hv);
            asm volatile("s_waitcnt vmcnt(0)" ::: "memory");   // h at coherence point
            if (lane == 0)
                __hip_atomic_store(flagp, (unsigned int)(step + 1),
                                   __ATOMIC_RELAXED, __HIP_MEMORY_SCOPE_AGENT);
            // out stores off the recurrence critical path
            if (PRED && duty) {
                #pragma unroll
                for (int r = 0; r < 4; ++r)
                    out[(size_t)(r0 + kq * 4 + r) * TC_ + (size_t)tout * C_ + j * 16 + jc] = pacc[r] + bp;
            }
        }
    } else if (ch == 0) {
        // relay wave c1: poll next step's producer flags DURING the tail,
        // then publish readiness via LDS (replaces the release barrier).
        wait_flags16<false>(fl, lane, (unsigned int)(step + 1));
        if (lane == 0) lds_signal(rel, (unsigned int)(step + 1));
    }
    // kh1ch1: nothing — proceeds to next step's rel spin.
}

__global__ __launch_bounds__(256, 1) void gru_persist(
    const unsigned short* __restrict__ WencT,
    const unsigned short* __restrict__ WdecT,
    const unsigned short* __restrict__ Wdec0T,
    const float* __restrict__ benc, const float* __restrict__ bdec, const float* __restrict__ bdec0,
    const float* __restrict__ x,
    unsigned short* __restrict__ h16,
    float* __restrict__ out,
    unsigned int* __restrict__ flags)
{
    __shared__ __align__(16) float Ored[2][64][20];
    __shared__ __align__(16) unsigned short Hst[16][32];
    __shared__ unsigned int rel, hd1;

    const int bid = blockIdx.x;
    const int g = bid & 15, j = bid >> 4;   // group, block-in-group
    const int tid = threadIdx.x;
    const int c = tid >> 6, lane = tid & 63;
    const int kh = c & 1, ch = c >> 1;
    const int jc = lane & 15, kq = lane >> 4;
    const int r0 = g * 16;
    const bool duty = (j < 4);
    unsigned int* fl = flags + g * 16 * 32;   // 16 flags x 32-dword stride
    unsigned int* flagp = fl + j * 32;        // this block's own 128B line
    const int n0 = j * 128 + ch * 64;         // this wave's 64 gate cols

    if (tid == 0) { rel = 0; hd1 = 0; }
    __syncthreads();

    float be[4], bd[4], bd0[4];
    #pragma unroll
    for (int q = 0; q < 4; ++q) {
        be[q]  = benc[n0 + q * 16 + jc];
        bd[q]  = bdec[n0 + q * 16 + jc];
        bd0[q] = bdec0[n0 + q * 16 + jc];
    }
    const float bp = duty ? bdec[2048 + j * 16 + jc] : 0.f;

    // half-K encoder weights in registers (36 frags, proven footprint)
    s16x8 bfr[36];
    #pragma unroll
    for (int i = 0; i < 9; ++i) {
        const int gks = kh * 9 + i;
        #pragma unroll
        for (int q = 0; q < 4; ++q)
            bfr[i * 4 + q] = *(const s16x8*)(WencT + (size_t)(n0 + q * 16 + jc) * 576 + gks * 32 + kq * 8);
    }
    s16x8 pfr[8];
    #pragma unroll
    for (int i = 0; i < 8; ++i) pfr[i] = s16x8{0,0,0,0,0,0,0,0};

    float h32[4] = {0.f, 0.f, 0.f, 0.f};
    int parity = 0;
    float4 xf[2][2];

    for (int step = 0; step < 1024; ++step) {
        const bool enc = step < 512;
        // early x issue (kh0 waves; in flight during rel spin)
        if (enc && kh == 0) {
            const float* xp = x + (size_t)(r0 + jc) * TC_ + (size_t)step * C_ + kq * 8;
            #pragma unroll
            for (int i2 = 0; i2 < 2; ++i2) {
                xf[i2][0] = *(const float4*)(xp + i2 * 32);
                xf[i2][1] = *(const float4*)(xp + i2 * 32 + 4);
            }
        }
        // phase-change weight reloads (one-time; overlap the wait)
        if (step == 512) {
            #pragma unroll
            for (int i = 0; i < 8; ++i) {
                const int gks = kh * 8 + i;
                #pragma unroll
                for (int q = 0; q < 4; ++q)
                    bfr[i * 4 + q] = *(const s16x8*)(Wdec0T + (size_t)(n0 + q * 16 + jc) * 512 + gks * 32 + kq * 8);
                if (duty && ch == 0)
                    pfr[i] = *(const s16x8*)(WdecT + (size_t)(2048 + j * 16 + jc) * 512 + gks * 32 + kq * 8);
            }
        } else if (step == 513) {
            #pragma unroll
            for (int i = 0; i < 8; ++i) {
                const int gks = kh * 8 + i;
                #pragma unroll
                for (int q = 0; q < 4; ++q)
                    bfr[i * 4 + q] = *(const s16x8*)(WdecT + (size_t)(n0 + q * 16 + jc) * 512 + gks * 32 + kq * 8);
            }
        }
        // barrier-free release: spin on LDS word published by relay wave c1
        if (step > 0) lds_wait(&rel, (unsigned int)step);

        const unsigned short* hin = h16 + (size_t)parity * BH_;
        unsigned short* hout = h16 + (size_t)(parity ^ 1) * BH_;

        if (enc)
            do_step<18, false>(hin, hout, bfr, pfr, xf, be,  bp, h32, out, 0,
                               fl, flagp, step, r0, j, kh, ch, lane, duty, Ored, Hst, &rel, &hd1);
        else if (step == 512)
            do_step<16, false>(hin, hout, bfr, pfr, xf, bd0, bp, h32, out, 0,
                               fl, flagp, step, r0, j, kh, ch, lane, duty, Ored, Hst, &rel, &hd1);
        else
            do_step<16, true >(hin, hout, bfr, pfr, xf, bd,  bp, h32, out, step - 513,
                               fl, flagp, step, r0, j, kh, ch, lane, duty, Ored, Hst, &rel, &hd1);

        parity ^= 1;
    }

    // final pred_{511} from h after last step (duty blocks only)
    if (duty) {
        wait_flags16<true>(fl, lane, 1024u);
        const unsigned short* hin = h16 + (size_t)parity * BH_;
        const unsigned short* hrow = hin + (size_t)(r0 + jc) * H_;
        f32x4 pacc = {0, 0, 0, 0};
        if (ch == 0) {
            s16x8 hf[8];
            #pragma unroll
            for (int i = 0; i < 8; ++i) {
                const int gks = kh * 8 + i;
                hf[i] = ldh16a(hrow + gks * 32 + kq * 8);
            }
            asm volatile("s_waitcnt vmcnt(0)" ::: "memory");
            __builtin_amdgcn_sched_barrier(0);
            #pragma unroll
            for (int i = 0; i < 8; ++i)
                pacc = __builtin_amdgcn_mfma_f32_16x16x32_bf16(hf[i], pfr[i], pacc, 0, 0, 0);
            if (kh == 1) *(f32x4*)&Ored[0][lane][16] = pacc;
        }
        asm volatile("s_waitcnt lgkmcnt(0)" ::: "memory");
        __builtin_amdgcn_s_barrier();
        __builtin_amdgcn_sched_barrier(0);
        if (kh == 0 && ch == 0) {
            f32x4 o = *(const f32x4*)&Ored[0][lane][16];
            pacc = pacc + o;
            #pragma unroll
            for (int r = 0; r < 4; ++r)
                out[(size_t)(r0 + kq * 4 + r) * TC_ + (size_t)511 * C_ + j * 16 + jc] = pacc[r] + bp;
        }
    }
}

// ---------------- host launcher ----------------

extern "C" void kernel_launch(void* const* d_in, const int* in_sizes, int n_in,
                              void* d_out, int out_size, void* d_ws, size_t ws_size,
                              hipStream_t stream) {
    const float* x    = (const float*)d_in[0];
    const float* eWih = (const float*)d_in[1];
    const float* eWhh = (const float*)d_in[2];
    const float* ebih = (const float*)d_in[3];
    const float* ebhh = (const float*)d_in[4];
    const float* dWih = (const float*)d_in[5];
    const float* dWhh = (const float*)d_in[6];
    const float* dbih = (const float*)d_in[7];
    const float* dbhh = (const float*)d_in[8];
    const float* Wout = (const float*)d_in[9];
    const float* bout = (const float*)d_in[10];

    size_t off = 0;
    auto carve = [&](size_t bytes) -> void* {
        off = (off + 255) & ~(size_t)255;
        void* p = (char*)d_ws + off;
        off += bytes;
        return p;
    };
    unsigned short* WencT  = (unsigned short*)carve((size_t)2048 * 576 * 2);
    unsigned short* WdecT  = (unsigned short*)carve((size_t)2112 * 512 * 2);
    unsigned short* Wdec0T = (unsigned short*)carve((size_t)2112 * 512 * 2);
    float* benc  = (float*)carve(2048 * 4);
    float* bdec  = (float*)carve(2112 * 4);
    float* bdec0 = (float*)carve(2112 * 4);
    unsigned short* h16 = (unsigned short*)carve((size_t)2 * BH_ * 2);
    unsigned int* flags = (unsigned int*)carve(16 * 16 * 32 * 4);  // 1 flag/block, own 128B line

    hipMemsetAsync(h16, 0, (size_t)2 * BH_ * 2, stream);
    hipMemsetAsync(flags, 0, 16 * 16 * 32 * 4, stream);

    prep_enc_k<<<(2048 * 576 + 255) / 256, 256, 0, stream>>>(eWih, eWhh, ebih, ebhh, WencT, benc);
    prep_dec_k<<<2112, 256, 0, stream>>>(dWih, dWhh, Wout, WdecT, Wdec0T);
    prep_dec_bias_k<<<9, 256, 0, stream>>>(dWih, dbih, dbhh, bout, bdec, bdec0);

    gru_persist<<<256, 256, 0, stream>>>(WencT, WdecT, Wdec0T, benc, bdec, bdec0,
                                         x, h16, (float*)d_out, flags);
}